// Round 1
// baseline (16.003 us; speedup 1.0000x reference)
//
#include <hip/hip_runtime.h>

#define CANVAS 28
#define TSTEPS 64

__global__ __launch_bounds__(256) void draw_image_kernel(
    const float* __restrict__ x,   // (B, T, 3)
    float* __restrict__ out)       // (B, 28, 28)
{
    const int b   = blockIdx.x;
    const int tid = threadIdx.x;

    __shared__ float s_in[TSTEPS * 3];        // strokes for this batch
    __shared__ float s_px[TSTEPS * CANVAS];   // exp table over x-coord (columns j)
    __shared__ float s_py[TSTEPS * CANVAS];   // inten * exp table over y-coord (rows i)

    // Stage strokes (192 floats, coalesced)
    if (tid < TSTEPS * 3) {
        s_in[tid] = x[b * (TSTEPS * 3) + tid];
    }
    __syncthreads();

    const float g = (CANVAS * 0.5f) * (CANVAS * 0.5f);  // 196 = (1/sigma)^2

    // Build tables: 2 * 64 * 28 = 3584 entries, 14 per thread
    for (int idx = tid; idx < 2 * TSTEPS * CANVAS; idx += 256) {
        const int which = idx / (TSTEPS * CANVAS);
        const int rem   = idx - which * (TSTEPS * CANVAS);
        const int t     = rem / CANVAS;
        const int c     = rem - t * CANVAS;
        const float r   = (float)c * (1.0f / CANVAS) - 0.5f;
        if (which == 0) {
            const float d = r - s_in[t * 3 + 0];   // x-coord
            s_px[rem] = __expf(-d * d * g);
        } else {
            const float d = r - s_in[t * 3 + 1];   // y-coord
            s_py[rem] = s_in[t * 3 + 2] * __expf(-d * d * g);
        }
    }
    __syncthreads();

    // Each thread owns up to 4 pixels; t-loop outer for ILP.
    int pi[4], pj[4];
    bool act[4];
    float v[4];
    #pragma unroll
    for (int k = 0; k < 4; ++k) {
        const int p = tid + k * 256;
        act[k] = (p < CANVAS * CANVAS);
        const int pp = act[k] ? p : 0;
        pi[k] = pp / CANVAS;
        pj[k] = pp - pi[k] * CANVAS;
        v[k] = 0.0f;
    }

    #pragma unroll 8
    for (int t = 0; t < TSTEPS; ++t) {
        const float* pyt = &s_py[t * CANVAS];
        const float* pxt = &s_px[t * CANVAS];
        #pragma unroll
        for (int k = 0; k < 4; ++k) {
            v[k] = fmaxf(v[k], pyt[pi[k]] * pxt[pj[k]]);
        }
    }

    float* outb = out + b * (CANVAS * CANVAS);
    #pragma unroll
    for (int k = 0; k < 4; ++k) {
        const int p = tid + k * 256;
        if (act[k]) {
            outb[p] = fminf(v[k], 1.0f);
        }
    }
}

extern "C" void kernel_launch(void* const* d_in, const int* in_sizes, int n_in,
                              void* d_out, int out_size, void* d_ws, size_t ws_size,
                              hipStream_t stream) {
    const float* x = (const float*)d_in[0];
    float* out = (float*)d_out;
    const int B = in_sizes[0] / (TSTEPS * 3);   // 1024
    draw_image_kernel<<<dim3(B), dim3(256), 0, stream>>>(x, out);
}

// Round 2
// 10.860 us; speedup vs baseline: 1.4737x; 1.4737x over previous
//
#include <hip/hip_runtime.h>

#define CANVAS 28
#define TSTEPS 64
#define GCONST 196.0f   // (SIZE/2)^2

// out[b,i,j] = min(1, max_t inten*exp(-g(rj-x)^2)*exp(-g(ri-y)^2))
//            = min(1, exp(P(i,j) + max_t [A_t + cx_t*rj + cy_t*ri]))
// A = ln(I) - g(x^2+y^2), cx = 2gx, cy = 2gy, P = -g(rj^2 + ri^2)
__global__ __launch_bounds__(256) void draw_image_kernel(
    const float* __restrict__ x,   // (B, 64, 3)
    float* __restrict__ out)       // (B, 28, 28)
{
    const int b   = blockIdx.x;
    const int tid = threadIdx.x;

    __shared__ float4 s_abc[TSTEPS];   // {A, cx, cy, _} per stroke

    if (tid < TSTEPS) {
        const float xv = x[b * (TSTEPS * 3) + tid * 3 + 0];
        const float yv = x[b * (TSTEPS * 3) + tid * 3 + 1];
        const float iv = x[b * (TSTEPS * 3) + tid * 3 + 2];
        const float li = __logf(iv);   // -inf for iv==0: flows correctly through fmax
        s_abc[tid] = make_float4(li - GCONST * (xv * xv + yv * yv),
                                 2.0f * GCONST * xv,
                                 2.0f * GCONST * yv, 0.0f);
    }
    __syncthreads();

    // 196 threads: each owns a 1x4 tile (row = tid/7, cols = (tid%7)*4 .. +3)
    if (tid < 196) {
        const int row = tid / 7;
        const int cg  = tid - row * 7;
        const float ri = (float)row * (1.0f / CANVAS) - 0.5f;
        float rj[4];
        #pragma unroll
        for (int k = 0; k < 4; ++k)
            rj[k] = (float)(cg * 4 + k) * (1.0f / CANVAS) - 0.5f;

        float m0 = -1e30f, m1 = -1e30f, m2 = -1e30f, m3 = -1e30f;

        #pragma unroll 8
        for (int t = 0; t < TSTEPS; ++t) {
            const float4 abc = s_abc[t];                       // broadcast b128
            const float h = __builtin_fmaf(abc.z, ri, abc.x);  // A + cy*ri
            m0 = fmaxf(m0, __builtin_fmaf(abc.y, rj[0], h));
            m1 = fmaxf(m1, __builtin_fmaf(abc.y, rj[1], h));
            m2 = fmaxf(m2, __builtin_fmaf(abc.y, rj[2], h));
            m3 = fmaxf(m3, __builtin_fmaf(abc.y, rj[3], h));
        }

        const float pc = -GCONST * ri * ri;
        float4 o;
        o.x = fminf(__expf(m0 + __builtin_fmaf(-GCONST, rj[0] * rj[0], pc)), 1.0f);
        o.y = fminf(__expf(m1 + __builtin_fmaf(-GCONST, rj[1] * rj[1], pc)), 1.0f);
        o.z = fminf(__expf(m2 + __builtin_fmaf(-GCONST, rj[2] * rj[2], pc)), 1.0f);
        o.w = fminf(__expf(m3 + __builtin_fmaf(-GCONST, rj[3] * rj[3], pc)), 1.0f);

        float* outp = out + b * (CANVAS * CANVAS) + row * CANVAS + cg * 4;
        *reinterpret_cast<float4*>(outp) = o;   // 16B aligned: 784,112,16 all %16==0
    }
}

extern "C" void kernel_launch(void* const* d_in, const int* in_sizes, int n_in,
                              void* d_out, int out_size, void* d_ws, size_t ws_size,
                              hipStream_t stream) {
    const float* x = (const float*)d_in[0];
    float* out = (float*)d_out;
    const int B = in_sizes[0] / (TSTEPS * 3);   // 1024
    draw_image_kernel<<<dim3(B), dim3(256), 0, stream>>>(x, out);
}